// Round 7
// baseline (262.456 us; speedup 1.0000x reference)
//
#include <hip/hip_runtime.h>
#include <hip/hip_bf16.h>
#include <stdint.h>

// SimpleSSM: y = (scan_t h=tanh(A*h + x@W_B^T + b_B)) @ W_C^T + b_C
// B=8, L=2048, D=1024.  All fp32 in/out.
// R7: R4 decomposition (separate x split-convert; all-gload_lds GEMMs) with
// the GEMM K-loop rebuilt as BK=32 double-buffered raw-barrier counted-vmcnt
// (T3/T4): loads stay in flight across barriers, never drained to 0 in the
// main loop. Split-fp16 GEMM1 is mandatory (R2/R3: plain bf16/fp16 both
// chaos-amplify to 0.25 absmax; splits pass at 0.0156).

using half8 = __attribute__((ext_vector_type(8))) _Float16;  // 8 fp16
using f32x4 = __attribute__((ext_vector_type(4))) float;

#define DEV __device__ __forceinline__

#if __has_builtin(__builtin_amdgcn_exp2f)
DEV float pexp(float x) { return __builtin_amdgcn_exp2f(x); }
constexpr float BX_SCALE = 2.8853900817779268f;   // 2*log2(e): exp2 domain
#else
DEV float pexp(float x) { return __expf(x); }
constexpr float BX_SCALE = 2.0f;                   // e^x domain
#endif

DEV ushort f2h(float x) {
  union { _Float16 f; ushort u; } c;
  c.f = (_Float16)x;          // v_cvt_f16_f32, RNE
  return c.u;
}
DEV float h2f(ushort u) {
  union { ushort u; _Float16 f; } c;
  c.u = u;
  return (float)c.f;
}

DEV void gload_lds16(const void* g, void* l) {
  __builtin_amdgcn_global_load_lds((const __attribute__((address_space(1))) void*)g,
                                   (__attribute__((address_space(3))) void*)l,
                                   16, 0, 0);
}

// ---------------- conversion kernels ----------------
// fp32 -> fp16 hi + fp16 lo (lo = fp16(x - hi)); residual ~2^-22*|x|.
__global__ void k_split_convert(const float* __restrict__ in, ushort* __restrict__ hi,
                                ushort* __restrict__ lo, int n4) {
  const int stride = gridDim.x * blockDim.x;
  for (int i = blockIdx.x * blockDim.x + threadIdx.x; i < n4; i += stride) {
    float4 v = reinterpret_cast<const float4*>(in)[i];
    ushort4 hv, lv;
    hv.x = f2h(v.x); lv.x = f2h(v.x - h2f(hv.x));
    hv.y = f2h(v.y); lv.y = f2h(v.y - h2f(hv.y));
    hv.z = f2h(v.z); lv.z = f2h(v.z - h2f(hv.z));
    hv.w = f2h(v.w); lv.w = f2h(v.w - h2f(hv.w));
    reinterpret_cast<ushort4*>(hi)[i] = hv;
    reinterpret_cast<ushort4*>(lo)[i] = lv;
  }
}

// W_B -> fp16 hi+lo split; W_C -> fp16.  One launch.
__global__ void k_convert_weights(const float* __restrict__ WB, const float* __restrict__ WC,
                                  ushort* __restrict__ wbh, ushort* __restrict__ wbl,
                                  ushort* __restrict__ wch, int n4) {
  const int stride = gridDim.x * blockDim.x;
  for (int i = blockIdx.x * blockDim.x + threadIdx.x; i < 2 * n4; i += stride) {
    if (i < n4) {
      float4 v = reinterpret_cast<const float4*>(WB)[i];
      ushort4 hv, lv;
      hv.x = f2h(v.x); lv.x = f2h(v.x - h2f(hv.x));
      hv.y = f2h(v.y); lv.y = f2h(v.y - h2f(hv.y));
      hv.z = f2h(v.z); lv.z = f2h(v.z - h2f(hv.z));
      hv.w = f2h(v.w); lv.w = f2h(v.w - h2f(hv.w));
      reinterpret_cast<ushort4*>(wbh)[i] = hv;
      reinterpret_cast<ushort4*>(wbl)[i] = lv;
    } else {
      const int j = i - n4;
      float4 v = reinterpret_cast<const float4*>(WC)[j];
      ushort4 hv;
      hv.x = f2h(v.x); hv.y = f2h(v.y);
      hv.z = f2h(v.z); hv.w = f2h(v.w);
      reinterpret_cast<ushort4*>(wch)[j] = hv;
    }
  }
}

// ---------------- GEMM (C = scale*(A @ B^T + bias)), fp16, counted-vmcnt ---
// 128x128 tile, BK=32, 4 waves (2x2), wave tile 64x64 (4x4 16x16x32 frags).
// Double-buffered LDS; raw s_barrier + counted s_waitcnt vmcnt(N): the next
// tile's global_load_lds stay in flight across barriers (drained to N = one
// batch, never 0 until the last step).  LDS tile stored as 64 lines x 128B
// (two 32-elem rows per line), swizzle byte ^= (line&3)<<4 applied on BOTH
// the staging source address and the ds_read address (rule #21).
// Per K-step per thread: 8 (split) / 4 gloads, 16 / 8 ds_read_b128,
// 48 / 16 MFMAs.
template <int SPLIT, int SCALE>
__global__ __launch_bounds__(256, SPLIT ? 2 : 4)
void k_gemm_bt(const ushort* __restrict__ Ah, const ushort* __restrict__ Al,
               const ushort* __restrict__ Bh, const ushort* __restrict__ Bl,
               const float* __restrict__ bias, float* __restrict__ C,
               int M, int N, int K) {
  constexpr int NMAT = SPLIT ? 4 : 2;
  // per-mat 128x32 fp16 = 8KB = 4096 ushorts; buffer = NMAT mats; x2 buffers
  __shared__ __align__(1024) ushort lds[2 * NMAT * 4096];

  const int t = threadIdx.x;
  const int lane = t & 63;
  const int w = t >> 6;
  const int wm = w >> 1, wn = w & 1;

  // XCD-bijective remap (grid 8 x 128): l=8*by+bx, xcd=l&7, s=l>>3;
  // bm=(s&~7)|xcd, bn=s&7.
  int bm, bn;
  {
    const int l = blockIdx.y * 8 + blockIdx.x;
    const int xcd = l & 7, s = l >> 3;
    bm = ((s >> 3) << 3) | xcd;
    bn = s & 7;
  }

  const int lr = lane & 15;               // fragment row within 16
  const int kcb = (lane >> 4) << 4;       // k byte offset 0/16/32/48 (8 elems)

  const ushort* gA_h = Ah + (size_t)(bm * 128) * K;
  const ushort* gA_l = SPLIT ? (Al + (size_t)(bm * 128) * K) : gA_h;
  const ushort* gB_h = Bh + (size_t)(bn * 128) * K;
  const ushort* gB_l = SPLIT ? (Bl + (size_t)(bn * 128) * K) : gB_h;

  f32x4 acc[4][4];
#pragma unroll
  for (int i = 0; i < 4; ++i)
#pragma unroll
    for (int j = 0; j < 4; ++j)
#pragma unroll
      for (int r = 0; r < 4; ++r) acc[i][j][r] = 0.f;

  // stage one 128x32 K-tile of all NMAT matrices into buffer `buf`.
  // LDS linear chunk lin16 (16B) holds: line=lin16>>3, half=(lin16>>2)&1,
  // cb=(lin16&3)<<4; element row=2*line+half, k-col byte = cb ^ (line&3)<<4.
  auto stage = [&](int kt, int buf) {
    const int k0 = kt * 32;
    ushort* base = lds + buf * (NMAT * 4096);
#pragma unroll
    for (int i = 0; i < 2; ++i) {
      const int lin16 = i * 256 + t;
      const int line = lin16 >> 3;
      const int row = (line << 1) | ((lin16 >> 2) & 1);
      const int kb = ((lin16 & 3) << 4) ^ ((line & 3) << 4);  // source swizzle
      const size_t goff = (size_t)row * K + (size_t)(k0 + (kb >> 1));
      const int dst = lin16 << 3;          // ushort index (x8 per 16B)
      gload_lds16(gA_h + goff, base + dst);
      gload_lds16(gB_h + goff, base + (SPLIT ? 2 : 1) * 4096 + dst);
      if (SPLIT) {
        gload_lds16(gA_l + goff, base + 4096 + dst);
        gload_lds16(gB_l + goff, base + 3 * 4096 + dst);
      }
    }
  };

  auto ldfrag = [&](const ushort* mat, int row) -> half8 {
    const int line = row >> 1;
    const int off = (line << 7) + ((row & 1) << 6) + (kcb ^ ((line & 3) << 4));
    return *reinterpret_cast<const half8*>(reinterpret_cast<const char*>(mat) + off);
  };

  const int NT = K / 32;                   // 32
  stage(0, 0);
  stage(1, 1);

  auto kstep = [&](int kt, bool last) {
    // wait for buffer kt's loads only (keep kt+1's batch in flight)
    if (last)        asm volatile("s_waitcnt vmcnt(0)" ::: "memory");
    else if (SPLIT)  asm volatile("s_waitcnt vmcnt(8)" ::: "memory");
    else             asm volatile("s_waitcnt vmcnt(4)" ::: "memory");
    __builtin_amdgcn_sched_barrier(0);
    __builtin_amdgcn_s_barrier();          // all threads' tile-kt loads done
    __builtin_amdgcn_sched_barrier(0);

    const ushort* base = lds + (kt & 1) * (NMAT * 4096);
    const ushort* sAh = base;
    const ushort* sAl = base + 4096;
    const ushort* sBh = base + (SPLIT ? 2 : 1) * 4096;
    const ushort* sBl = base + 3 * 4096;

    half8 ah[4], al[4], bh[4], bl[4];
#pragma unroll
    for (int i = 0; i < 4; ++i) {
      const int r = wm * 64 + i * 16 + lr;
      ah[i] = ldfrag(sAh, r);
      if (SPLIT) al[i] = ldfrag(sAl, r);
    }
#pragma unroll
    for (int j = 0; j < 4; ++j) {
      const int r = wn * 64 + j * 16 + lr;
      bh[j] = ldfrag(sBh, r);
      if (SPLIT) bl[j] = ldfrag(sBl, r);
    }
#pragma unroll
    for (int i = 0; i < 4; ++i)
#pragma unroll
      for (int j = 0; j < 4; ++j) {
        acc[i][j] = __builtin_amdgcn_mfma_f32_16x16x32_f16(ah[i], bh[j], acc[i][j], 0, 0, 0);
        if (SPLIT) {
          acc[i][j] = __builtin_amdgcn_mfma_f32_16x16x32_f16(al[i], bh[j], acc[i][j], 0, 0, 0);
          acc[i][j] = __builtin_amdgcn_mfma_f32_16x16x32_f16(ah[i], bl[j], acc[i][j], 0, 0, 0);
        }
      }

    __builtin_amdgcn_sched_barrier(0);
    __builtin_amdgcn_s_barrier();          // all reads of buffer kt done
    if (kt + 2 < NT) stage(kt + 2, kt & 1);  // overwrite freed buffer; stays in flight
  };

  for (int kt = 0; kt < NT - 1; ++kt) kstep(kt, false);
  kstep(NT - 1, true);

  // Epilogue: C/D layout col=lane&15, row=(lane>>4)*4+reg  [m89]
  float* Cb = C + (size_t)(bm * 128) * N + bn * 128;
#pragma unroll
  for (int i = 0; i < 4; ++i)
#pragma unroll
    for (int j = 0; j < 4; ++j) {
      const int col = wn * 64 + j * 16 + lr;
      const float bv = bias[bn * 128 + col];
#pragma unroll
      for (int r = 0; r < 4; ++r) {
        const int rowt = wm * 64 + i * 16 + ((lane >> 4) << 2) + r;
        float o = acc[i][j][r] + bv;
        if (SCALE) o *= BX_SCALE;
        Cb[(size_t)rowt * N + col] = o;
      }
    }
}

// ---------------- sequential recurrence ----------------
// Bx2 = BX_SCALE*(x@W_B^T + b_B).  State r with h = 1-2r (r_init = 0.5).
// Critical chain per step (4 dep ops):
//   u2 = fma(-2a2, r, c_t)  ->  p = exp2(u2)  ->  q = p+1  ->  r = rcp(q)
// c_t = a2 + bx_t precomputed off-chain; output h_t = fma(-2,r,1)+cvt+store
// also off-chain.  No clamp: |u2| <= ~27, exp2 cannot overflow.
// Ping-pong double buffer: each buffer reloads under the other's 32 steps.
__global__ __launch_bounds__(64)
void k_recurrence(const float* __restrict__ Bx2, const float* __restrict__ Avec,
                  ushort* __restrict__ Hout) {
  const int tid = blockIdx.x * 64 + threadIdx.x;   // 0..8191
  const int b = tid >> 10;
  const int d = tid & 1023;
  const float a2 = BX_SCALE * Avec[d];
  const float na2 = -2.f * a2;
  const float* bx = Bx2 + (size_t)b * 2048 * 1024 + d;
  ushort* ho = Hout + (size_t)b * 2048 * 1024 + d;

  constexpr int P = 32;
  constexpr int NC = 2048 / P;   // 64 chunks, even
  float cA[P], cB[P];
#pragma unroll
  for (int i = 0; i < P; ++i) cA[i] = a2 + bx[(size_t)i * 1024];
#pragma unroll
  for (int i = 0; i < P; ++i) cB[i] = a2 + bx[(size_t)(P + i) * 1024];

  float r = 0.5f;
  for (int c = 0; c < NC; c += 2) {
#pragma unroll
    for (int i = 0; i < P; ++i) {
      const float u2 = fmaf(na2, r, cA[i]);
      r = __builtin_amdgcn_rcpf(pexp(u2) + 1.f);
      ho[(size_t)(c * P + i) * 1024] = f2h(fmaf(-2.f, r, 1.f));
    }
    if (c + 2 < NC) {
#pragma unroll
      for (int i = 0; i < P; ++i) cA[i] = a2 + bx[(size_t)((c + 2) * P + i) * 1024];
    }
#pragma unroll
    for (int i = 0; i < P; ++i) {
      const float u2 = fmaf(na2, r, cB[i]);
      r = __builtin_amdgcn_rcpf(pexp(u2) + 1.f);
      ho[(size_t)((c + 1) * P + i) * 1024] = f2h(fmaf(-2.f, r, 1.f));
    }
    if (c + 3 < NC) {
#pragma unroll
      for (int i = 0; i < P; ++i) cB[i] = a2 + bx[(size_t)((c + 3) * P + i) * 1024];
    }
  }
}

// ---------------- launch ----------------
extern "C" void kernel_launch(void* const* d_in, const int* in_sizes, int n_in,
                              void* d_out, int out_size, void* d_ws, size_t ws_size,
                              hipStream_t stream) {
  const float* x   = (const float*)d_in[0];
  const float* A   = (const float*)d_in[1];
  const float* W_B = (const float*)d_in[2];
  const float* b_B = (const float*)d_in[3];
  const float* W_C = (const float*)d_in[4];
  const float* b_C = (const float*)d_in[5];
  float* y = (float*)d_out;

  const int Bsz = 8, L = 2048, D = 1024;
  const int M = Bsz * L;                       // 16384

  char* ws = (char*)d_ws;
  ushort* x_hi = (ushort*)(ws);                 // 32MB fp16
  ushort* x_lo = (ushort*)(ws + 33554432);      // 32MB fp16
  ushort* wbh  = (ushort*)(ws + 67108864);      // 2MB
  ushort* wbl  = (ushort*)(ws + 69206016);      // 2MB
  ushort* wch  = (ushort*)(ws + 71303168);      // 2MB
  float*  Bx   = (float*)(ws + 73400320);       // 64MB fp32 scaled
  ushort* h    = x_hi;                          // alias (dead after GEMM1)

  k_split_convert<<<2048, 256, 0, stream>>>(x, x_hi, x_lo, M * D / 4);
  k_convert_weights<<<512, 256, 0, stream>>>(W_B, W_C, wbh, wbl, wch, D * D / 4);

  k_gemm_bt<1, 1><<<dim3(8, M / 128), 256, 0, stream>>>(
      x_hi, x_lo, wbh, wbl, b_B, Bx, M, D, D);

  k_recurrence<<<(Bsz * D) / 64, 64, 0, stream>>>(Bx, A, h);

  k_gemm_bt<0, 0><<<dim3(8, M / 128), 256, 0, stream>>>(
      h, (const ushort*)nullptr, wch, (const ushort*)nullptr, b_C, y, M, D, D);
}

// Round 8
// 229.953 us; speedup vs baseline: 1.1413x; 1.1413x over previous
//
#include <hip/hip_runtime.h>
#include <hip/hip_bf16.h>
#include <stdint.h>

// SimpleSSM: y = (scan_t h=tanh(A*h + x@W_B^T + b_B)) @ W_C^T + b_C
// B=8, L=2048, D=1024.  All fp32 in/out.
// R8 = R4 (measured-best GEMM structure: BK=64, 2-barrier, gload_lds,
// XCD-bijective remap) + GEMM2 at 4 blocks/CU + A folded into GEMM1
// epilogue + single convert kernel. Split-fp16 GEMM1 is mandatory
// (R2/R3: plain bf16/fp16 chaos-amplify to 0.25 absmax; splits pass).

using half8 = __attribute__((ext_vector_type(8))) _Float16;  // 8 fp16
using f32x4 = __attribute__((ext_vector_type(4))) float;

#define DEV __device__ __forceinline__

#if __has_builtin(__builtin_amdgcn_exp2f)
DEV float pexp(float x) { return __builtin_amdgcn_exp2f(x); }
constexpr float BX_SCALE = 2.8853900817779268f;   // 2*log2(e): exp2 domain
#else
DEV float pexp(float x) { return __expf(x); }
constexpr float BX_SCALE = 2.0f;                   // e^x domain
#endif

DEV ushort f2h(float x) {
  union { _Float16 f; ushort u; } c;
  c.f = (_Float16)x;          // v_cvt_f16_f32, RNE
  return c.u;
}
DEV float h2f(ushort u) {
  union { ushort u; _Float16 f; } c;
  c.u = u;
  return (float)c.f;
}

DEV void gload_lds16(const void* g, void* l) {
  __builtin_amdgcn_global_load_lds((const __attribute__((address_space(1))) void*)g,
                                   (__attribute__((address_space(3))) void*)l,
                                   16, 0, 0);
}

// ---------------- single conversion kernel ----------------
// x -> fp16 hi+lo; W_B -> fp16 hi+lo; W_C -> fp16.  One launch.
__global__ void k_convert_all(const float* __restrict__ X, const float* __restrict__ WB,
                              const float* __restrict__ WC,
                              ushort* __restrict__ xh, ushort* __restrict__ xl,
                              ushort* __restrict__ wbh, ushort* __restrict__ wbl,
                              ushort* __restrict__ wch, int n4x, int n4w) {
  const int stride = gridDim.x * blockDim.x;
  const int total = n4x + 2 * n4w;
  for (int i = blockIdx.x * blockDim.x + threadIdx.x; i < total; i += stride) {
    if (i < n4x) {
      float4 v = reinterpret_cast<const float4*>(X)[i];
      ushort4 hv, lv;
      hv.x = f2h(v.x); lv.x = f2h(v.x - h2f(hv.x));
      hv.y = f2h(v.y); lv.y = f2h(v.y - h2f(hv.y));
      hv.z = f2h(v.z); lv.z = f2h(v.z - h2f(hv.z));
      hv.w = f2h(v.w); lv.w = f2h(v.w - h2f(hv.w));
      reinterpret_cast<ushort4*>(xh)[i] = hv;
      reinterpret_cast<ushort4*>(xl)[i] = lv;
    } else if (i < n4x + n4w) {
      const int j = i - n4x;
      float4 v = reinterpret_cast<const float4*>(WB)[j];
      ushort4 hv, lv;
      hv.x = f2h(v.x); lv.x = f2h(v.x - h2f(hv.x));
      hv.y = f2h(v.y); lv.y = f2h(v.y - h2f(hv.y));
      hv.z = f2h(v.z); lv.z = f2h(v.z - h2f(hv.z));
      hv.w = f2h(v.w); lv.w = f2h(v.w - h2f(hv.w));
      reinterpret_cast<ushort4*>(wbh)[j] = hv;
      reinterpret_cast<ushort4*>(wbl)[j] = lv;
    } else {
      const int j = i - n4x - n4w;
      float4 v = reinterpret_cast<const float4*>(WC)[j];
      ushort4 hv;
      hv.x = f2h(v.x); hv.y = f2h(v.y);
      hv.z = f2h(v.z); hv.w = f2h(v.w);
      reinterpret_cast<ushort4*>(wch)[j] = hv;
    }
  }
}

// ---------------- GEMM (C = A @ B^T + bias [, +Avec, *BX_SCALE]) -----------
// A:[M,K] B:[N,K] fp16. 128x128 tile, BK=64, 4 waves (2x2), wave 64x64 via
// 4x4 16x16x32 MFMAs.  SPLIT: acc += Ah*Bh + Al*Bh + Ah*Bl (3 MFMAs).
// LDS XOR-swizzle (byte ^= (row&7)<<4) via pre-swizzled global source +
// swizzled ds_read (rule #21). XCD-bijective remap: xcd owns bm ≡ xcd
// (mod 8); weight panel L2-resident per XCD.  SCALE epilogue:
// C = BX_SCALE*(acc + bias[col] + Avec[col])  (A-term folded for recurrence).
template <int SPLIT, int SCALE, int MINWAVES>
__global__ __launch_bounds__(256, MINWAVES)
void k_gemm_bt(const ushort* __restrict__ Ah, const ushort* __restrict__ Al,
               const ushort* __restrict__ Bh, const ushort* __restrict__ Bl,
               const float* __restrict__ bias, const float* __restrict__ Avec,
               float* __restrict__ C, int M, int N, int K) {
  constexpr int NMAT = SPLIT ? 4 : 2;
  __shared__ __align__(1024) ushort lds[NMAT * 128 * 64];
  ushort* sAh = lds;
  ushort* sAl = lds + (SPLIT ? 8192 : 0);
  ushort* sBh = lds + (SPLIT ? 16384 : 8192);
  ushort* sBl = lds + (SPLIT ? 24576 : 8192);

  const int t = threadIdx.x;
  const int lane = t & 63;
  const int w = t >> 6;
  const int wm = w >> 1, wn = w & 1;

  // XCD-bijective remap (grid 8 x 128): l=8*by+bx, xcd=l&7 (round-robin
  // dispatch), s=l>>3; bm=(s&~7)|xcd, bn=s&7.
  int bm, bn;
  {
    const int l = blockIdx.y * 8 + blockIdx.x;
    const int xcd = l & 7, s = l >> 3;
    bm = ((s >> 3) << 3) | xcd;
    bn = s & 7;
  }

  const int lr = lane & 15;           // fragment row/col within 16
  const int lk = (lane >> 4) << 3;    // k offset 0/8/16/24

  const ushort* gA_h = Ah + (size_t)(bm * 128) * K;
  const ushort* gA_l = SPLIT ? (Al + (size_t)(bm * 128) * K) : gA_h;
  const ushort* gB_h = Bh + (size_t)(bn * 128) * K;
  const ushort* gB_l = SPLIT ? (Bl + (size_t)(bn * 128) * K) : gB_h;

  f32x4 acc[4][4];
#pragma unroll
  for (int i = 0; i < 4; ++i)
#pragma unroll
    for (int j = 0; j < 4; ++j)
#pragma unroll
      for (int r = 0; r < 4; ++r) acc[i][j][r] = 0.f;

  auto stage = [&](int kt) {
    const int k0 = kt * 64;
#pragma unroll
    for (int i = 0; i < 4; ++i) {
      const int lin16 = i * 256 + t;          // 16B-chunk index, linear in LDS
      const int lb = lin16 << 4;              // LDS byte offset
      const int row = lb >> 7;                // 128B (=64 elems) per row
      const int srcb = (lb & 127) ^ ((row & 7) << 4);  // inverse swizzle on SOURCE
      const size_t goff = (size_t)row * K + (size_t)(k0 + (srcb >> 1));
      const int lidx = i * 2048 + w * 512;    // wave-uniform LDS base (ushort idx)
      gload_lds16(gA_h + goff, sAh + lidx);
      if (SPLIT) gload_lds16(gA_l + goff, sAl + lidx);
      gload_lds16(gB_h + goff, sBh + lidx);
      if (SPLIT) gload_lds16(gB_l + goff, sBl + lidx);
    }
  };

  auto ldfrag = [&](const ushort* s, int row, int kc) -> half8 {
    const int byte = (row << 7) + (((kc << 1) ^ ((row & 7) << 4)));
    return *reinterpret_cast<const half8*>(reinterpret_cast<const char*>(s) + byte);
  };

  const int NT = K / 64;
  stage(0);
  for (int kt = 0; kt < NT; ++kt) {
    __syncthreads();   // staged data visible (compiler drains vmcnt here)
#pragma unroll
    for (int kk = 0; kk < 2; ++kk) {
      half8 ah[4], bh[4], al[4], bl[4];
      const int kc = kk * 32 + lk;
#pragma unroll
      for (int i = 0; i < 4; ++i) {
        const int row = wm * 64 + i * 16 + lr;
        ah[i] = ldfrag(sAh, row, kc);
        if (SPLIT) al[i] = ldfrag(sAl, row, kc);
      }
#pragma unroll
      for (int j = 0; j < 4; ++j) {
        const int row = wn * 64 + j * 16 + lr;
        bh[j] = ldfrag(sBh, row, kc);
        if (SPLIT) bl[j] = ldfrag(sBl, row, kc);
      }
#pragma unroll
      for (int i = 0; i < 4; ++i)
#pragma unroll
        for (int j = 0; j < 4; ++j) {
          acc[i][j] = __builtin_amdgcn_mfma_f32_16x16x32_f16(ah[i], bh[j], acc[i][j], 0, 0, 0);
          if (SPLIT) {
            acc[i][j] = __builtin_amdgcn_mfma_f32_16x16x32_f16(al[i], bh[j], acc[i][j], 0, 0, 0);
            acc[i][j] = __builtin_amdgcn_mfma_f32_16x16x32_f16(ah[i], bl[j], acc[i][j], 0, 0, 0);
          }
        }
    }
    __syncthreads();   // all reads done before overwrite
    if (kt + 1 < NT) stage(kt + 1);
  }

  // Epilogue: C/D layout col=lane&15, row=(lane>>4)*4+reg  [m89]
  float* Cb = C + (size_t)(bm * 128) * N + bn * 128;
#pragma unroll
  for (int i = 0; i < 4; ++i)
#pragma unroll
    for (int j = 0; j < 4; ++j) {
      const int col = wn * 64 + j * 16 + lr;
      float bv = bias[bn * 128 + col];
      if (SCALE) bv += Avec[bn * 128 + col];   // fold A-vector for recurrence
#pragma unroll
      for (int r = 0; r < 4; ++r) {
        const int rowt = wm * 64 + i * 16 + ((lane >> 4) << 2) + r;
        float o = acc[i][j][r] + bv;
        if (SCALE) o *= BX_SCALE;
        Cb[(size_t)rowt * N + col] = o;
      }
    }
}

// ---------------- sequential recurrence ----------------
// Bx2 holds BX_SCALE*(x@W_B^T + b_B + A)  (A-term pre-folded in GEMM1).
// State r with h = 1-2r (r_init = 0.5).  Critical chain per step (4 dep ops):
//   u2 = fma(-2a2, r, c_t)  ->  p = exp2(u2)  ->  q = p+1  ->  r = rcp(q)
// u2 = a2*(1-2r) + BX_SCALE*(xW+b) = BX_SCALE*(A*h + xW + b).  Output
// h_t = fma(-2,r,1)+cvt+store off-chain.  No clamp: |u2| <= ~27.
// Ping-pong double buffer: each buffer reloads under the other's 32 steps.
__global__ __launch_bounds__(64)
void k_recurrence(const float* __restrict__ Bx2, const float* __restrict__ Avec,
                  ushort* __restrict__ Hout) {
  const int tid = blockIdx.x * 64 + threadIdx.x;   // 0..8191
  const int b = tid >> 10;
  const int d = tid & 1023;
  const float na2 = -2.f * BX_SCALE * Avec[d];
  const float* bx = Bx2 + (size_t)b * 2048 * 1024 + d;
  ushort* ho = Hout + (size_t)b * 2048 * 1024 + d;

  constexpr int P = 32;
  constexpr int NC = 2048 / P;   // 64 chunks, even
  float cA[P], cB[P];
#pragma unroll
  for (int i = 0; i < P; ++i) cA[i] = bx[(size_t)i * 1024];
#pragma unroll
  for (int i = 0; i < P; ++i) cB[i] = bx[(size_t)(P + i) * 1024];

  float r = 0.5f;
  for (int c = 0; c < NC; c += 2) {
#pragma unroll
    for (int i = 0; i < P; ++i) {
      const float u2 = fmaf(na2, r, cA[i]);
      r = __builtin_amdgcn_rcpf(pexp(u2) + 1.f);
      ho[(size_t)(c * P + i) * 1024] = f2h(fmaf(-2.f, r, 1.f));
    }
    if (c + 2 < NC) {
#pragma unroll
      for (int i = 0; i < P; ++i) cA[i] = bx[(size_t)((c + 2) * P + i) * 1024];
    }
#pragma unroll
    for (int i = 0; i < P; ++i) {
      const float u2 = fmaf(na2, r, cB[i]);
      r = __builtin_amdgcn_rcpf(pexp(u2) + 1.f);
      ho[(size_t)((c + 1) * P + i) * 1024] = f2h(fmaf(-2.f, r, 1.f));
    }
    if (c + 3 < NC) {
#pragma unroll
      for (int i = 0; i < P; ++i) cB[i] = bx[(size_t)((c + 3) * P + i) * 1024];
    }
  }
}

// ---------------- launch ----------------
extern "C" void kernel_launch(void* const* d_in, const int* in_sizes, int n_in,
                              void* d_out, int out_size, void* d_ws, size_t ws_size,
                              hipStream_t stream) {
  const float* x   = (const float*)d_in[0];
  const float* A   = (const float*)d_in[1];
  const float* W_B = (const float*)d_in[2];
  const float* b_B = (const float*)d_in[3];
  const float* W_C = (const float*)d_in[4];
  const float* b_C = (const float*)d_in[5];
  float* y = (float*)d_out;

  const int Bsz = 8, L = 2048, D = 1024;
  const int M = Bsz * L;                       // 16384

  char* ws = (char*)d_ws;
  ushort* x_hi = (ushort*)(ws);                 // 32MB fp16
  ushort* x_lo = (ushort*)(ws + 33554432);      // 32MB fp16
  ushort* wbh  = (ushort*)(ws + 67108864);      // 2MB
  ushort* wbl  = (ushort*)(ws + 69206016);      // 2MB
  ushort* wch  = (ushort*)(ws + 71303168);      // 2MB
  float*  Bx   = (float*)(ws + 73400320);       // 64MB fp32 scaled
  ushort* h    = x_hi;                          // alias (dead after GEMM1)

  k_convert_all<<<2048, 256, 0, stream>>>(x, W_B, W_C, x_hi, x_lo, wbh, wbl, wch,
                                          M * D / 4, D * D / 4);

  k_gemm_bt<1, 1, 2><<<dim3(8, M / 128), 256, 0, stream>>>(
      x_hi, x_lo, wbh, wbl, b_B, A, Bx, M, D, D);

  k_recurrence<<<(Bsz * D) / 64, 64, 0, stream>>>(Bx, A, h);

  k_gemm_bt<0, 0, 4><<<dim3(8, M / 128), 256, 0, stream>>>(
      h, (const ushort*)nullptr, wch, (const ushort*)nullptr, b_C,
      (const float*)nullptr, y, M, D, D);
}